// Round 1
// baseline (288.398 us; speedup 1.0000x reference)
//
#include <hip/hip_runtime.h>
#include <cmath>
#include <stdint.h>

// ---------------------------------------------------------------------------
// AttentionLayer: att = softmax((q@W1+b1) @ (k@W2+b2)^T / sqrt(Sk)) @ v
// B=4, SQ=SK=2048, D=UNITS=1024, fp32 in/out, bf16 MFMA internally.
// R5: GEMM engine rebuilt as the 256x256 8-phase counted-vmcnt template
//     (T2 swizzle + T3/T4 8-phase counted vmcnt + T5 setprio).
//     512 thr = 8 waves (2Mx4N), BK=64, LDS 128 KiB as [buf][khalf][256][32]
//     so staging units die per-phase -> vmcnt(6) steady state, never 0.
// ---------------------------------------------------------------------------

typedef short short8 __attribute__((ext_vector_type(8)));
typedef float f32x4 __attribute__((ext_vector_type(4)));
typedef __bf16 bf16x8 __attribute__((ext_vector_type(8)));

typedef __attribute__((address_space(3))) void lds_void;
typedef __attribute__((address_space(1))) void gbl_void;

__device__ __forceinline__ unsigned short f2b(float x) {
    unsigned u = __builtin_bit_cast(unsigned, x);
    u += 0x7fffu + ((u >> 16) & 1u);
    return (unsigned short)(u >> 16);
}

// ---------------------------------------------------------------------------
// Fused prep: z = 0..3 v-batch transpose, 4..5 W1/W2 transpose,
//             6..7 q cast, 8..9 k cast.  grid (64, 32, 10) x 256 thr.
// ---------------------------------------------------------------------------
__global__ void prep_kernel(const float* __restrict__ q,
                            const float* __restrict__ k,
                            const float* __restrict__ v,
                            const float* __restrict__ W1,
                            const float* __restrict__ W2,
                            unsigned short* __restrict__ qbf,
                            unsigned short* __restrict__ kbf,
                            unsigned short* __restrict__ vT,
                            unsigned short* __restrict__ W1t,
                            unsigned short* __restrict__ W2t) {
    __shared__ float tile[32][33];
    const int bz = blockIdx.z;
    const int t = threadIdx.x;

    if (bz >= 6) {
        // ---- cast path: 2048 elems per block ----
        const float* in = (bz < 8) ? q : k;
        unsigned short* out = (bz < 8) ? qbf : kbf;
        const long zi = (bz - 6) & 1;
        const long fb = zi * 2048 + blockIdx.y * 64 + blockIdx.x;
        const long i = (fb * 256 + t) * 8;
        float4 a = *(const float4*)(in + i);
        float4 b = *(const float4*)(in + i + 4);
        union { short8 v8; unsigned short u[8]; } r;
        r.u[0] = f2b(a.x); r.u[1] = f2b(a.y); r.u[2] = f2b(a.z); r.u[3] = f2b(a.w);
        r.u[4] = f2b(b.x); r.u[5] = f2b(b.y); r.u[6] = f2b(b.z); r.u[7] = f2b(b.w);
        *(short8*)(out + i) = r.v8;
        return;
    }

    // ---- transpose path ----
    const float* in;
    unsigned short* out;
    int R, C;
    if (bz < 4) {
        R = 2048; C = 1024;
        in = v + (long)bz * R * C;
        out = vT + (long)bz * R * C;
    } else {
        R = 1024; C = 1024;
        if (blockIdx.x >= 32) return;
        in = (bz == 4) ? W1 : W2;
        out = (bz == 4) ? W1t : W2t;
    }
    const int rt = blockIdx.x * 32, ct = blockIdx.y * 32;
    {
        int r = t >> 3, c4 = (t & 7) * 4;
        float4 a = *(const float4*)(in + (long)(rt + r) * C + ct + c4);
        tile[r][c4 + 0] = a.x; tile[r][c4 + 1] = a.y;
        tile[r][c4 + 2] = a.z; tile[r][c4 + 3] = a.w;
    }
    __syncthreads();
    {
        int c = t >> 3, rg = (t & 7) * 4;
        ushort4 o;
        o.x = f2b(tile[rg + 0][c]); o.y = f2b(tile[rg + 1][c]);
        o.z = f2b(tile[rg + 2][c]); o.w = f2b(tile[rg + 3][c]);
        *(ushort4*)(out + (long)(ct + c) * R + rt + rg) = o;
    }
}

// ---------------------------------------------------------------------------
// bf16 GEMM: C[M][N] = A[M][K] * Bt[N][K]^T
// 256x256 tile, BK=64, 512 thr = 8 waves (2Mx4N), 8-phase counted-vmcnt.
// LDS [buf][khalf][256 rows][4 chunks x 8 bf16]; swizzle: phys_chunk =
// logical ^ ((row>>1)&3)  (inverse applied to per-lane GLOBAL source so the
// global_load_lds destination stays linear — both-sides-or-neither rule).
// Staging unit = one khalf of A or B (16 KB = 2 loads/thread). Stage stream
// runs 3 units ahead of compute -> s_waitcnt vmcnt(6) at phases 4/8 only.
// Region-death schedule (verified on paper):
//   buf0: A_K0 read P1 (restage P2) | B_K0 read P1,P2 (P3) | A_K1 read P3 (P4)
//         | B_K1 read P3,P4 (P5);  buf1 mirrors at P5..P8 / next P1.
// MODE 0: bf16 out, + bias (bias1 when bz==1)
// MODE 1: bf16 out = exp(acc*scale), atomicAdd per-row sums into rowsum
// MODE 2: fp32 out = acc / rowsum[row]
// ---------------------------------------------------------------------------

#define BARRIER() do { asm volatile("" ::: "memory"); \
    __builtin_amdgcn_s_barrier(); \
    asm volatile("" ::: "memory"); } while (0)

#define VMC6 asm volatile("s_waitcnt vmcnt(6)" ::: "memory")
#define NOPSTMT do {} while (0)

#define STG(P0, P1, LBASE, KO) do { \
    const long ko_ = (KO); \
    __builtin_amdgcn_global_load_lds((gbl_void*)((P0) + ko_), \
        (lds_void*)((LBASE) + stgoff), 16, 0, 0); \
    __builtin_amdgcn_global_load_lds((gbl_void*)((P1) + ko_), \
        (lds_void*)((LBASE) + stgoff + 4096), 16, 0, 0); \
} while (0)

#define KOFF(T_, KH_) ((long)((((T_) < nTile) ? (T_) : ((T_) - nTile)) * 64 + (KH_) * 32))

#define LDA_(BUF, KH, I_) __builtin_bit_cast(bf16x8, \
    *(const short8*)(&As[BUF][KH][aoff + (I_) * 512]))
#define LDB_(BUF, KH, J_) __builtin_bit_cast(bf16x8, \
    *(const short8*)(&Bs[BUF][KH][boff + (J_) * 512]))

#define MFMA_PAIR(JA, JB) do { \
    _Pragma("unroll") \
    for (int i_ = 0; i_ < 8; i_++) { \
        acc[i_][JA] = __builtin_amdgcn_mfma_f32_16x16x32_bf16(a[i_], b[JA], acc[i_][JA], 0, 0, 0); \
        acc[i_][JB] = __builtin_amdgcn_mfma_f32_16x16x32_bf16(a[i_], b[JB], acc[i_][JB], 0, 0, 0); \
    } \
} while (0)

#define PHASE_A(BUF, KH, STAGE_STMT, TAIL_STMT) do { \
    _Pragma("unroll") \
    for (int i_ = 0; i_ < 8; i_++) a[i_] = LDA_(BUF, KH, i_); \
    b[0] = LDB_(BUF, KH, 0); \
    b[1] = LDB_(BUF, KH, 1); \
    STAGE_STMT; \
    BARRIER(); \
    __builtin_amdgcn_s_setprio(1); \
    MFMA_PAIR(0, 1); \
    __builtin_amdgcn_s_setprio(0); \
    TAIL_STMT; \
    BARRIER(); \
} while (0)

#define PHASE_B(BUF, KH, STAGE_STMT, TAIL_STMT) do { \
    b[2] = LDB_(BUF, KH, 2); \
    b[3] = LDB_(BUF, KH, 3); \
    STAGE_STMT; \
    BARRIER(); \
    __builtin_amdgcn_s_setprio(1); \
    MFMA_PAIR(2, 3); \
    __builtin_amdgcn_s_setprio(0); \
    TAIL_STMT; \
    BARRIER(); \
} while (0)

template <int MODE>
__global__ __launch_bounds__(512, 2) void gemm_bt_kernel(
                               const unsigned short* __restrict__ A,
                               const unsigned short* __restrict__ Bt,
                               const float* __restrict__ bias0,
                               const float* __restrict__ bias1,
                               float* __restrict__ rowsum,
                               void* __restrict__ Cout,
                               int M, int N, int K,
                               float scale,
                               long sA, long sB, long sC) {
    // [buf][khalf][256 rows * 32 bf16] = 4 x 16 KB per operand = 128 KiB total
    __shared__ __align__(16) unsigned short As[2][2][8192];
    __shared__ __align__(16) unsigned short Bs[2][2][8192];

    // ---- XCD-aware tile remap (bijective; all our grids have y*z % 8 == 0) ----
    int bx, by, bz;
    {
        const int nx = gridDim.x;
        const int Rt = gridDim.y * gridDim.z;
        if ((Rt & 7) == 0) {
            int flat = ((int)blockIdx.z * gridDim.y + blockIdx.y) * nx + blockIdx.x;
            int rpx = Rt >> 3;
            int c = flat & 7;
            int j = flat >> 3;
            bx = j / rpx;
            int yg = c * rpx + (j - bx * rpx);
            bz = yg / gridDim.y;
            by = yg - bz * gridDim.y;
        } else {
            bx = blockIdx.x; by = blockIdx.y; bz = blockIdx.z;
        }
    }

    A  += (long)bz * sA;
    Bt += (long)bz * sB;

    const int tid = threadIdx.x;
    const int lane = tid & 63;
    const int w = tid >> 6;            // wave 0..7
    const int wm = w >> 2, wn = w & 3; // 2Mx4N -> per-wave 128x64 output
    const int row0 = by * 256;
    const int col0 = bx * 256;

    // ---- staging addressing: one issue = 64 lanes x 16B = 16 rows of 32 bf16.
    // lane l -> row (l>>2), phys chunk (l&3); global logical chunk =
    // (l&3) ^ ((l>>3)&3)  == phys ^ ((row>>1)&3)   (inverse swizzle at source)
    const int srow = lane >> 2;
    const int sch  = (lane & 3) ^ ((lane >> 3) & 3);
    const unsigned short* pA0 = A  + (long)(row0 + w * 16 + srow) * K + sch * 8;
    const unsigned short* pA1 = pA0 + (long)128 * K;
    const unsigned short* pB0 = Bt + (long)(col0 + w * 16 + srow) * K + sch * 8;
    const unsigned short* pB1 = pB0 + (long)128 * K;
    const int stgoff = w * 512;        // wave-uniform LDS base within a unit

    // ---- fragment read addressing: row = (wm*128|wn*64) + f*16 + lr,
    // logical chunk q = lane>>4, phys = q ^ ((lr>>1)&3) -> 8 distinct 16B
    // bank positions, 2 lanes each (free 2-way, same profile as R4's 0-conflict)
    const int lr = lane & 15, quad = lane >> 4;
    const int rch  = (quad ^ ((lr >> 1) & 3)) * 8;
    const int aoff = (wm * 128 + lr) * 32 + rch;
    const int boff = (wn * 64  + lr) * 32 + rch;

    const int nTile = K >> 6;   // 64-wide K tiles (>= 16 for all our shapes)
    const int nIter = K >> 7;   // 2 tiles per iteration

    f32x4 acc[8][4];
#pragma unroll
    for (int i = 0; i < 8; i++)
#pragma unroll
        for (int j = 0; j < 4; j++) acc[i][j] = f32x4{0.f, 0.f, 0.f, 0.f};
    bf16x8 a[8], b[4];

    // ---- prologue: T0 fully + T1 {A_K0,B_K0,A_K1}; vmcnt(6) retires T0 ----
    STG(pA0, pA1, &As[0][0][0], KOFF(0, 0));
    STG(pB0, pB1, &Bs[0][0][0], KOFF(0, 0));
    STG(pA0, pA1, &As[0][1][0], KOFF(0, 1));
    STG(pB0, pB1, &Bs[0][1][0], KOFF(0, 1));
    STG(pA0, pA1, &As[1][0][0], KOFF(1, 0));
    STG(pB0, pB1, &Bs[1][0][0], KOFF(1, 0));
    STG(pA0, pA1, &As[1][1][0], KOFF(1, 1));
    VMC6;
    BARRIER();

    // ---- main loop: iter computes T=2it (buf0, P1-4) and T=2it+1 (buf1, P5-8).
    // Stage stream: P1:T1.B1  P2:T2.A0  P3:T2.B0  P4:T2.A1 [vmcnt6]
    //               P5:T2.B1  P6:T3.A0  P7:T3.B0  P8:T3.A1 [vmcnt6]
    // (final-iter overshoot tiles clamp to 0/1: harmless re-loads, never read)
    for (int it = 0; it < nIter; ++it) {
        const int t1 = 2 * it + 1, t2 = 2 * it + 2, t3 = 2 * it + 3;
        PHASE_A(0, 0, STG(pB0, pB1, &Bs[1][1][0], KOFF(t1, 1)), NOPSTMT);
        PHASE_B(0, 0, STG(pA0, pA1, &As[0][0][0], KOFF(t2, 0)), NOPSTMT);
        PHASE_A(0, 1, STG(pB0, pB1, &Bs[0][0][0], KOFF(t2, 0)), NOPSTMT);
        PHASE_B(0, 1, STG(pA0, pA1, &As[0][1][0], KOFF(t2, 1)), VMC6);
        PHASE_A(1, 0, STG(pB0, pB1, &Bs[0][1][0], KOFF(t2, 1)), NOPSTMT);
        PHASE_B(1, 0, STG(pA0, pA1, &As[1][0][0], KOFF(t3, 0)), NOPSTMT);
        PHASE_A(1, 1, STG(pB0, pB1, &Bs[1][0][0], KOFF(t3, 0)), NOPSTMT);
        PHASE_B(1, 1, STG(pA0, pA1, &As[1][1][0], KOFF(t3, 1)), VMC6);
    }
    // drain stray clamped stages before endpgm (LDS handed to next block)
    asm volatile("s_waitcnt vmcnt(0)" ::: "memory");

    // ---- epilogue (C/D layout: col = lane&15, row = quad*4 + reg) ----
    const long cbase = (long)bz * sC;

    if (MODE == 0) {
        const float* bp = (bz && bias1) ? bias1 : bias0;
#pragma unroll
        for (int j = 0; j < 4; j++) {
            const int gcol = col0 + wn * 64 + j * 16 + lr;
            const float bv = bp[gcol];
#pragma unroll
            for (int i = 0; i < 8; i++) {
                const int growb = row0 + wm * 128 + i * 16 + quad * 4;
#pragma unroll
                for (int r = 0; r < 4; r++) {
                    float val = acc[i][j][r] * scale + bv;
                    ((unsigned short*)Cout)[cbase + (long)(growb + r) * N + gcol] = f2b(val);
                }
            }
        }
    } else if (MODE == 1) {
        float psum[8][4];
#pragma unroll
        for (int i = 0; i < 8; i++)
#pragma unroll
            for (int r = 0; r < 4; r++) psum[i][r] = 0.f;
#pragma unroll
        for (int j = 0; j < 4; j++) {
            const int gcol = col0 + wn * 64 + j * 16 + lr;
#pragma unroll
            for (int i = 0; i < 8; i++) {
                const int growb = row0 + wm * 128 + i * 16 + quad * 4;
#pragma unroll
                for (int r = 0; r < 4; r++) {
                    float e = __expf(acc[i][j][r] * scale);
                    psum[i][r] += e;
                    ((unsigned short*)Cout)[cbase + (long)(growb + r) * N + gcol] = f2b(e);
                }
            }
        }
        // reduce across the 16 lr lanes (xor masks 1,2,4,8 keep quad bits)
#pragma unroll
        for (int i = 0; i < 8; i++)
#pragma unroll
            for (int r = 0; r < 4; r++) {
                float s = psum[i][r];
                s += __shfl_xor(s, 1);
                s += __shfl_xor(s, 2);
                s += __shfl_xor(s, 4);
                s += __shfl_xor(s, 8);
                if (lr == 0) {
                    const int grow = row0 + wm * 128 + i * 16 + quad * 4 + r;
                    atomicAdd(rowsum + (long)bz * M + grow, s);
                }
            }
    } else {  // MODE == 2
#pragma unroll
        for (int i = 0; i < 8; i++) {
            const int growb = row0 + wm * 128 + i * 16 + quad * 4;
#pragma unroll
            for (int r = 0; r < 4; r++) {
                const float inv = 1.0f / rowsum[(long)bz * M + growb + r];
#pragma unroll
                for (int j = 0; j < 4; j++) {
                    const int gcol = col0 + wn * 64 + j * 16 + lr;
                    ((float*)Cout)[cbase + (long)(growb + r) * N + gcol] =
                        acc[i][j][r] * inv;
                }
            }
        }
    }
}

// ---------------------------------------------------------------------------
extern "C" void kernel_launch(void* const* d_in, const int* in_sizes, int n_in,
                              void* d_out, int out_size, void* d_ws, size_t ws_size,
                              hipStream_t stream) {
    const float* q   = (const float*)d_in[0];
    const float* k   = (const float*)d_in[1];
    const float* v   = (const float*)d_in[2];
    const float* W1w = (const float*)d_in[3];
    const float* W1b = (const float*)d_in[4];
    const float* W2w = (const float*)d_in[5];
    const float* W2b = (const float*)d_in[6];
    float* out = (float*)d_out;

    const int B = 4, SQ = 2048, SK = 2048, D = 1024, U = 1024;
    char* ws = (char*)d_ws;
    const size_t MB = 1024 * 1024;
    unsigned short* qbf = (unsigned short*)(ws + 0);        // 16 MB
    unsigned short* kbf = (unsigned short*)(ws + 16 * MB);  // 16 MB
    unsigned short* vT  = (unsigned short*)(ws + 32 * MB);  // 16 MB [B][D][SK]
    unsigned short* W1t = (unsigned short*)(ws + 48 * MB);  // 2 MB  [U][D]
    unsigned short* W2t = (unsigned short*)(ws + 50 * MB);  // 2 MB  (dead after l1l2)
    unsigned short* l1  = (unsigned short*)(ws + 52 * MB);  // 16 MB [B*SQ][U]
    unsigned short* l2  = (unsigned short*)(ws + 68 * MB);  // 16 MB
    unsigned short* sc  = (unsigned short*)(ws + 0);        // 32 MB [B][SQ][SK]
    float* rowsum = (float*)(ws + 50 * MB);                 // 32 KB, reuses W2t slot

    // 1: all preprocessing (q/k cast, v/W1/W2 transpose)
    prep_kernel<<<dim3(64, 32, 10), 256, 0, stream>>>(
        q, k, v, W1w, W2w, qbf, kbf, vT, W1t, W2t);
    // 2: merged l1 = q@W1+b1 (bz=0), l2 = k@W2+b2 (bz=1)  (bf16 out)
    gemm_bt_kernel<0><<<dim3(U / 256, (B * SQ) / 256, 2), 512, 0, stream>>>(
        qbf, W1t, W1b, W2b, nullptr, l1, B * SQ, U, D, 1.0f,
        (long)8 * 1024 * 1024, (long)1024 * 1024, (long)8 * 1024 * 1024);
    // 3: zero rowsum (W2t now dead; stream order guarantees safety)
    hipMemsetAsync(rowsum, 0, (size_t)B * SQ * sizeof(float), stream);
    // 4: sc = exp(l1 @ l2^T / sqrt(SK)) bf16 + rowsum atomics
    const float invs = 1.0f / sqrtf((float)SK);
    gemm_bt_kernel<1><<<dim3(SK / 256, SQ / 256, B), 512, 0, stream>>>(
        l1, l2, nullptr, nullptr, rowsum, sc, SQ, SK, U, invs,
        (long)SQ * U, (long)SK * U, (long)SQ * SK);
    // 5: att = (sc @ vT^T) / rowsum[row]  (fp32 out)  -- 128 blocks (half-CU)
    gemm_bt_kernel<2><<<dim3(D / 256, SQ / 256, B), 512, 0, stream>>>(
        sc, vT, nullptr, nullptr, rowsum, out, SQ, D, SK, 1.0f,
        (long)SQ * SK, (long)D * SK, (long)SQ * D);
}